// Round 1
// baseline (158.829 us; speedup 1.0000x reference)
//
#include <hip/hip_runtime.h>
#include <math.h>

#define BB 48
#define SS 1024
#define NROW (BB * SS)

// Kernel 1: per-band projections + cross attention + BN partial sums.
// grid = 3 combos * 48 batches * 4 query-chunks = 576 blocks, 128 threads,
// 2 queries per thread. K/V staged transposed in LDS ([3][1024]) so the
// inner loop does broadcast ds_read_b128 (conflict-free).
__global__ __launch_bounds__(128) void mbfca_attn(
    const float* __restrict__ x,
    const float* __restrict__ WQ, const float* __restrict__ bQ,
    const float* __restrict__ WK, const float* __restrict__ bK,
    const float* __restrict__ WV, const float* __restrict__ bV,
    float* __restrict__ ws_out, float* __restrict__ ws_acc)
{
    const int bid   = blockIdx.x;
    const int c     = bid / (BB * 4);      // combo 0..2
    const int rem   = bid % (BB * 4);
    const int b     = rem >> 2;            // batch
    const int chunk = rem & 3;             // query chunk of 256
    // combo c: Q band = (c+2)%3, K band = c, V band = (c+1)%3
    const int kband = c;
    const int vband = (c + 1) % 3;
    const int qband = (c + 2) % 3;

    __shared__ __align__(16) float Ks[3][SS];
    __shared__ __align__(16) float Vs[3][SS];
    __shared__ float red[2][6];

    const int tid = threadIdx.x;

    // uniform weight loads (scalar-load friendly)
    float wk[9], wv[9], wq[9], bk[3], bv[3], bq[3];
    #pragma unroll
    for (int i = 0; i < 9; ++i) {
        wk[i] = WK[kband * 9 + i];
        wv[i] = WV[vband * 9 + i];
        wq[i] = WQ[qband * 9 + i];
    }
    #pragma unroll
    for (int i = 0; i < 3; ++i) {
        bk[i] = bK[kband * 3 + i];
        bv[i] = bV[vband * 3 + i];
        bq[i] = bQ[qband * 3 + i];
    }

    const float* xk = x + (size_t)(kband * BB + b) * SS * 3;
    const float* xv = x + (size_t)(vband * BB + b) * SS * 3;
    const float* xq = x + (size_t)(qband * BB + b) * SS * 3;

    // stage K,V (projected) into LDS, transposed
    #pragma unroll
    for (int i = 0; i < 8; ++i) {
        int t = tid + (i << 7);
        float a0 = xk[t * 3 + 0], a1 = xk[t * 3 + 1], a2 = xk[t * 3 + 2];
        Ks[0][t] = wk[0] * a0 + wk[1] * a1 + wk[2] * a2 + bk[0];
        Ks[1][t] = wk[3] * a0 + wk[4] * a1 + wk[5] * a2 + bk[1];
        Ks[2][t] = wk[6] * a0 + wk[7] * a1 + wk[8] * a2 + bk[2];
        float c0 = xv[t * 3 + 0], c1 = xv[t * 3 + 1], c2 = xv[t * 3 + 2];
        Vs[0][t] = wv[0] * c0 + wv[1] * c1 + wv[2] * c2 + bv[0];
        Vs[1][t] = wv[3] * c0 + wv[4] * c1 + wv[5] * c2 + bv[1];
        Vs[2][t] = wv[6] * c0 + wv[7] * c1 + wv[8] * c2 + bv[2];
    }
    __syncthreads();

    // 2 queries per thread; fold 1/sqrt(3) into q
    const float rs3 = 0.57735026918962576f;
    float q[2][3], mx[2];
    #pragma unroll
    for (int j = 0; j < 2; ++j) {
        int s = (chunk << 8) + (j << 7) + tid;
        float a0 = xq[s * 3 + 0], a1 = xq[s * 3 + 1], a2 = xq[s * 3 + 2];
        q[j][0] = (wq[0] * a0 + wq[1] * a1 + wq[2] * a2 + bq[0]) * rs3;
        q[j][1] = (wq[3] * a0 + wq[4] * a1 + wq[5] * a2 + bq[1]) * rs3;
        q[j][2] = (wq[6] * a0 + wq[7] * a1 + wq[8] * a2 + bq[2]) * rs3;
        mx[j] = -3.0e38f;
    }

    const float4* K0 = reinterpret_cast<const float4*>(&Ks[0][0]);
    const float4* K1 = reinterpret_cast<const float4*>(&Ks[1][0]);
    const float4* K2 = reinterpret_cast<const float4*>(&Ks[2][0]);
    const float4* V0 = reinterpret_cast<const float4*>(&Vs[0][0]);
    const float4* V1 = reinterpret_cast<const float4*>(&Vs[1][0]);
    const float4* V2 = reinterpret_cast<const float4*>(&Vs[2][0]);

    // pass 1: row max
    for (int t4 = 0; t4 < SS / 4; ++t4) {
        float4 k0 = K0[t4], k1 = K1[t4], k2 = K2[t4];
        #pragma unroll
        for (int j = 0; j < 2; ++j) {
            float s0 = q[j][0] * k0.x + q[j][1] * k1.x + q[j][2] * k2.x;
            float s1 = q[j][0] * k0.y + q[j][1] * k1.y + q[j][2] * k2.y;
            float s2 = q[j][0] * k0.z + q[j][1] * k1.z + q[j][2] * k2.z;
            float s3 = q[j][0] * k0.w + q[j][1] * k1.w + q[j][2] * k2.w;
            mx[j] = fmaxf(mx[j], fmaxf(fmaxf(s0, s1), fmaxf(s2, s3)));
        }
    }

    // pass 2: exp-sum + PV accumulate
    float l[2]  = {0.f, 0.f};
    float A0[2] = {0.f, 0.f}, A1[2] = {0.f, 0.f}, A2[2] = {0.f, 0.f};
    for (int t4 = 0; t4 < SS / 4; ++t4) {
        float4 k0 = K0[t4], k1 = K1[t4], k2 = K2[t4];
        float4 v0 = V0[t4], v1 = V1[t4], v2 = V2[t4];
        #pragma unroll
        for (int j = 0; j < 2; ++j) {
            float s0 = q[j][0] * k0.x + q[j][1] * k1.x + q[j][2] * k2.x;
            float s1 = q[j][0] * k0.y + q[j][1] * k1.y + q[j][2] * k2.y;
            float s2 = q[j][0] * k0.z + q[j][1] * k1.z + q[j][2] * k2.z;
            float s3 = q[j][0] * k0.w + q[j][1] * k1.w + q[j][2] * k2.w;
            float p0 = __expf(s0 - mx[j]);
            float p1 = __expf(s1 - mx[j]);
            float p2 = __expf(s2 - mx[j]);
            float p3 = __expf(s3 - mx[j]);
            l[j]  += (p0 + p1) + (p2 + p3);
            A0[j] += p0 * v0.x + p1 * v0.y + p2 * v0.z + p3 * v0.w;
            A1[j] += p0 * v1.x + p1 * v1.y + p2 * v1.z + p3 * v1.w;
            A2[j] += p0 * v2.x + p1 * v2.y + p2 * v2.z + p3 * v2.w;
        }
    }

    // write attention output rows + accumulate BN partials
    float part[6];
    #pragma unroll
    for (int k = 0; k < 6; ++k) part[k] = 0.f;
    #pragma unroll
    for (int j = 0; j < 2; ++j) {
        int s = (chunk << 8) + (j << 7) + tid;
        float inv = 1.0f / l[j];
        float o0 = A0[j] * inv, o1 = A1[j] * inv, o2 = A2[j] * inv;
        float* dst = ws_out + (size_t)(b * SS + s) * 9 + 3 * c;
        dst[0] = o0; dst[1] = o1; dst[2] = o2;
        part[0] += o0; part[1] += o1; part[2] += o2;
        part[3] += o0 * o0; part[4] += o1 * o1; part[5] += o2 * o2;
    }

    // wave-64 butterfly reduce, then cross-wave via LDS, one atomic set/block
    #pragma unroll
    for (int off = 32; off >= 1; off >>= 1) {
        #pragma unroll
        for (int k = 0; k < 6; ++k)
            part[k] += __shfl_xor(part[k], off, 64);
    }
    if ((tid & 63) == 0) {
        #pragma unroll
        for (int k = 0; k < 6; ++k) red[tid >> 6][k] = part[k];
    }
    __syncthreads();
    if (tid == 0) {
        #pragma unroll
        for (int e = 0; e < 3; ++e) {
            atomicAdd(&ws_acc[3 * c + e],     red[0][e]     + red[1][e]);
            atomicAdd(&ws_acc[9 + 3 * c + e], red[0][3 + e] + red[1][3 + e]);
        }
    }
}

// Kernel 2: BatchNorm (batch stats from ws_acc) + FC. Memory-bound, tiny.
__global__ __launch_bounds__(256) void mbfca_bnfc(
    const float* __restrict__ ws_out, const float* __restrict__ ws_acc,
    const float* __restrict__ gamma, const float* __restrict__ beta,
    const float* __restrict__ fcw, const float* __restrict__ fcb,
    float* __restrict__ out)
{
    const int row = blockIdx.x * 256 + threadIdx.x;  // 0..49151
    const float invN = 1.0f / (float)NROW;
    float sc[9], sh[9];
    #pragma unroll
    for (int ch = 0; ch < 9; ++ch) {
        float mean = ws_acc[ch] * invN;
        float var  = ws_acc[9 + ch] * invN - mean * mean;  // biased variance
        float s = gamma[ch] * rsqrtf(var + 1e-5f);
        sc[ch] = s;
        sh[ch] = beta[ch] - mean * s;
    }
    const float* r = ws_out + (size_t)row * 9;
    float y0 = fcb[0], y1 = fcb[1], y2 = fcb[2];
    #pragma unroll
    for (int ch = 0; ch < 9; ++ch) {
        float n = r[ch] * sc[ch] + sh[ch];
        y0 += n * fcw[ch];
        y1 += n * fcw[9 + ch];
        y2 += n * fcw[18 + ch];
    }
    out[row * 3 + 0] = y0;
    out[row * 3 + 1] = y1;
    out[row * 3 + 2] = y2;
}

extern "C" void kernel_launch(void* const* d_in, const int* in_sizes, int n_in,
                              void* d_out, int out_size, void* d_ws, size_t ws_size,
                              hipStream_t stream)
{
    const float* x     = (const float*)d_in[0];
    const float* WQ    = (const float*)d_in[1];
    const float* bQv   = (const float*)d_in[2];
    const float* WK    = (const float*)d_in[3];
    const float* bKv   = (const float*)d_in[4];
    const float* WV    = (const float*)d_in[5];
    const float* bVv   = (const float*)d_in[6];
    const float* gamma = (const float*)d_in[7];
    const float* beta  = (const float*)d_in[8];
    const float* fcw   = (const float*)d_in[9];
    const float* fcb   = (const float*)d_in[10];

    float* ws_out = (float*)d_ws;                       // NROW*9 floats
    float* ws_acc = ws_out + (size_t)NROW * 9;          // 18 floats (sum, sumsq)

    hipMemsetAsync(ws_acc, 0, 18 * sizeof(float), stream);
    mbfca_attn<<<dim3(3 * BB * 4), dim3(128), 0, stream>>>(
        x, WQ, bQv, WK, bKv, WV, bVv, ws_out, ws_acc);
    mbfca_bnfc<<<dim3(NROW / 256), dim3(256), 0, stream>>>(
        ws_out, ws_acc, gamma, beta, fcw, fcb, (float*)d_out);
}

// Round 2
// 83.526 us; speedup vs baseline: 1.9016x; 1.9016x over previous
//
#include <hip/hip_runtime.h>
#include <math.h>

#define BB 48
#define SS 1024
#define KS 4                  // key slices per (combo,batch)
#define SSK (SS / KS)         // 256 keys per slice
#define NCB (3 * BB)          // 144 combo-batches
#define NROW (BB * SS)

// ws layout:
//   part[KS][NCB][SS][4]  (A0,A1,A2,l) partial sums   = 9,437,184 B
//   acc[18]               BN sum / sumsq              (zeroed each launch)
#define PART_FLOATS ((size_t)KS * NCB * SS * 4)

// Kernel 1: projection + no-max single-pass attention partials.
// grid = NCB*KS = 576 blocks, 256 threads, 4 queries/thread, 256-key slice
// staged (projected) in LDS planar [3][256] so inner loop is broadcast
// ds_read_b128 (conflict-free). Partials written to per-slice buffers
// (deterministic, no atomics).
__global__ __launch_bounds__(256) void mbfca_attn(
    const float* __restrict__ x,
    const float* __restrict__ WQ, const float* __restrict__ bQ,
    const float* __restrict__ WK, const float* __restrict__ bK,
    const float* __restrict__ WV, const float* __restrict__ bV,
    float* __restrict__ part)
{
    const int bid   = blockIdx.x;
    const int cb    = bid >> 2;          // combo-batch 0..143
    const int slice = bid & (KS - 1);
    const int c     = cb / BB;           // combo
    const int b     = cb % BB;           // batch
    const int kband = c;
    const int vband = (c + 1) % 3;
    const int qband = (c + 2) % 3;

    __shared__ __align__(16) float Ksm[3][SSK];
    __shared__ __align__(16) float Vsm[3][SSK];

    const int tid = threadIdx.x;

    // uniform weights
    float wk[9], wv[9], wq[9], bk[3], bv[3], bq[3];
    #pragma unroll
    for (int i = 0; i < 9; ++i) {
        wk[i] = WK[kband * 9 + i];
        wv[i] = WV[vband * 9 + i];
        wq[i] = WQ[qband * 9 + i];
    }
    #pragma unroll
    for (int i = 0; i < 3; ++i) {
        bk[i] = bK[kband * 3 + i];
        bv[i] = bV[vband * 3 + i];
        bq[i] = bQ[qband * 3 + i];
    }

    const float* xk = x + (size_t)(kband * BB + b) * SS * 3;
    const float* xv = x + (size_t)(vband * BB + b) * SS * 3;
    const float* xq = x + (size_t)(qband * BB + b) * SS * 3;

    // stage this slice's projected K,V (256 keys, one iter with 256 threads)
    {
        const int t = slice * SSK + tid;
        float a0 = xk[t * 3 + 0], a1 = xk[t * 3 + 1], a2 = xk[t * 3 + 2];
        Ksm[0][tid] = wk[0] * a0 + wk[1] * a1 + wk[2] * a2 + bk[0];
        Ksm[1][tid] = wk[3] * a0 + wk[4] * a1 + wk[5] * a2 + bk[1];
        Ksm[2][tid] = wk[6] * a0 + wk[7] * a1 + wk[8] * a2 + bk[2];
        float c0 = xv[t * 3 + 0], c1 = xv[t * 3 + 1], c2 = xv[t * 3 + 2];
        Vsm[0][tid] = wv[0] * c0 + wv[1] * c1 + wv[2] * c2 + bv[0];
        Vsm[1][tid] = wv[3] * c0 + wv[4] * c1 + wv[5] * c2 + bv[1];
        Vsm[2][tid] = wv[6] * c0 + wv[7] * c1 + wv[8] * c2 + bv[2];
    }
    __syncthreads();

    // 4 queries/thread (contiguous: s = 4*tid + jj); fold 1/sqrt(3) into q
    const float rs3 = 0.57735026918962576f;
    float q0[4], q1[4], q2[4];
    {
        const float4* xq4 = reinterpret_cast<const float4*>(xq + 12 * tid);
        float4 A = xq4[0], B4 = xq4[1], C4 = xq4[2];
        float a[12] = {A.x, A.y, A.z, A.w, B4.x, B4.y, B4.z, B4.w,
                       C4.x, C4.y, C4.z, C4.w};
        #pragma unroll
        for (int j = 0; j < 4; ++j) {
            float a0 = a[j * 3 + 0], a1 = a[j * 3 + 1], a2 = a[j * 3 + 2];
            q0[j] = (wq[0] * a0 + wq[1] * a1 + wq[2] * a2 + bq[0]) * rs3;
            q1[j] = (wq[3] * a0 + wq[4] * a1 + wq[5] * a2 + bq[1]) * rs3;
            q2[j] = (wq[6] * a0 + wq[7] * a1 + wq[8] * a2 + bq[2]) * rs3;
        }
    }

    float l[4]  = {0.f, 0.f, 0.f, 0.f};
    float A0[4] = {0.f, 0.f, 0.f, 0.f};
    float A1[4] = {0.f, 0.f, 0.f, 0.f};
    float A2[4] = {0.f, 0.f, 0.f, 0.f};

    const float4* K0 = reinterpret_cast<const float4*>(&Ksm[0][0]);
    const float4* K1 = reinterpret_cast<const float4*>(&Ksm[1][0]);
    const float4* K2 = reinterpret_cast<const float4*>(&Ksm[2][0]);
    const float4* V0 = reinterpret_cast<const float4*>(&Vsm[0][0]);
    const float4* V1 = reinterpret_cast<const float4*>(&Vsm[1][0]);
    const float4* V2 = reinterpret_cast<const float4*>(&Vsm[2][0]);

    for (int t4 = 0; t4 < SSK / 4; ++t4) {   // 64 iterations
        float4 k0 = K0[t4], k1 = K1[t4], k2 = K2[t4];
        float4 v0 = V0[t4], v1 = V1[t4], v2 = V2[t4];
        #pragma unroll
        for (int j = 0; j < 4; ++j) {
            float s0 = q0[j] * k0.x + q1[j] * k1.x + q2[j] * k2.x;
            float s1 = q0[j] * k0.y + q1[j] * k1.y + q2[j] * k2.y;
            float s2 = q0[j] * k0.z + q1[j] * k1.z + q2[j] * k2.z;
            float s3 = q0[j] * k0.w + q1[j] * k1.w + q2[j] * k2.w;
            float p0 = __expf(s0);
            float p1 = __expf(s1);
            float p2 = __expf(s2);
            float p3 = __expf(s3);
            l[j]  += (p0 + p1) + (p2 + p3);
            A0[j] += p0 * v0.x + p1 * v0.y + p2 * v0.z + p3 * v0.w;
            A1[j] += p0 * v1.x + p1 * v1.y + p2 * v1.z + p3 * v1.w;
            A2[j] += p0 * v2.x + p1 * v2.y + p2 * v2.z + p3 * v2.w;
        }
    }

    // deterministic per-slice store: part[slice][cb][4*tid+j] = (A0,A1,A2,l)
    float4* dst = reinterpret_cast<float4*>(part) +
                  ((size_t)(slice * NCB + cb) * SS + 4 * tid);
    #pragma unroll
    for (int j = 0; j < 4; ++j)
        dst[j] = make_float4(A0[j], A1[j], A2[j], l[j]);
}

// Kernel 2: reduce slices -> attention out (on the fly), BN sum/sumsq
// partials -> 18 atomics/block.
__global__ __launch_bounds__(256) void mbfca_stats(
    const float* __restrict__ part, float* __restrict__ acc)
{
    const int r = blockIdx.x * 256 + threadIdx.x;   // row 0..49151
    const int b = r >> 10, s = r & 1023;
    __shared__ float red[4][18];

    float sums[18];
    #pragma unroll
    for (int k = 0; k < 18; ++k) sums[k] = 0.f;

    const float4* p4 = reinterpret_cast<const float4*>(part);
    #pragma unroll
    for (int c = 0; c < 3; ++c) {
        const int cb = c * BB + b;
        float4 t = make_float4(0.f, 0.f, 0.f, 0.f);
        #pragma unroll
        for (int sl = 0; sl < KS; ++sl) {
            float4 u = p4[(size_t)(sl * NCB + cb) * SS + s];
            t.x += u.x; t.y += u.y; t.z += u.z; t.w += u.w;
        }
        float inv = 1.0f / t.w;
        float o0 = t.x * inv, o1 = t.y * inv, o2 = t.z * inv;
        sums[3 * c + 0] = o0;       sums[3 * c + 1] = o1;       sums[3 * c + 2] = o2;
        sums[9 + 3 * c + 0] = o0 * o0; sums[9 + 3 * c + 1] = o1 * o1; sums[9 + 3 * c + 2] = o2 * o2;
    }

    #pragma unroll
    for (int off = 32; off >= 1; off >>= 1)
        #pragma unroll
        for (int k = 0; k < 18; ++k)
            sums[k] += __shfl_xor(sums[k], off, 64);

    const int tid = threadIdx.x;
    if ((tid & 63) == 0) {
        #pragma unroll
        for (int k = 0; k < 18; ++k) red[tid >> 6][k] = sums[k];
    }
    __syncthreads();
    if (tid < 18)
        atomicAdd(&acc[tid], red[0][tid] + red[1][tid] + red[2][tid] + red[3][tid]);
}

// Kernel 3: recompute attention out from slices, apply BN + FC, write y.
__global__ __launch_bounds__(256) void mbfca_bnfc(
    const float* __restrict__ part, const float* __restrict__ acc,
    const float* __restrict__ gamma, const float* __restrict__ beta,
    const float* __restrict__ fcw, const float* __restrict__ fcb,
    float* __restrict__ out)
{
    const int r = blockIdx.x * 256 + threadIdx.x;
    const int b = r >> 10, s = r & 1023;
    const float invN = 1.0f / (float)NROW;

    float sc[9], sh[9];
    #pragma unroll
    for (int ch = 0; ch < 9; ++ch) {
        float mean = acc[ch] * invN;
        float var  = acc[9 + ch] * invN - mean * mean;  // biased variance
        float sfac = gamma[ch] * rsqrtf(var + 1e-5f);
        sc[ch] = sfac;
        sh[ch] = beta[ch] - mean * sfac;
    }

    const float4* p4 = reinterpret_cast<const float4*>(part);
    float y0 = fcb[0], y1 = fcb[1], y2 = fcb[2];
    #pragma unroll
    for (int c = 0; c < 3; ++c) {
        const int cb = c * BB + b;
        float4 t = make_float4(0.f, 0.f, 0.f, 0.f);
        #pragma unroll
        for (int sl = 0; sl < KS; ++sl) {
            float4 u = p4[(size_t)(sl * NCB + cb) * SS + s];
            t.x += u.x; t.y += u.y; t.z += u.z; t.w += u.w;
        }
        float inv = 1.0f / t.w;
        float o[3] = {t.x * inv, t.y * inv, t.z * inv};
        #pragma unroll
        for (int e = 0; e < 3; ++e) {
            float n = o[e] * sc[3 * c + e] + sh[3 * c + e];
            y0 += n * fcw[3 * c + e];
            y1 += n * fcw[9 + 3 * c + e];
            y2 += n * fcw[18 + 3 * c + e];
        }
    }
    out[r * 3 + 0] = y0;
    out[r * 3 + 1] = y1;
    out[r * 3 + 2] = y2;
}

extern "C" void kernel_launch(void* const* d_in, const int* in_sizes, int n_in,
                              void* d_out, int out_size, void* d_ws, size_t ws_size,
                              hipStream_t stream)
{
    const float* x     = (const float*)d_in[0];
    const float* WQ    = (const float*)d_in[1];
    const float* bQv   = (const float*)d_in[2];
    const float* WK    = (const float*)d_in[3];
    const float* bKv   = (const float*)d_in[4];
    const float* WV    = (const float*)d_in[5];
    const float* bVv   = (const float*)d_in[6];
    const float* gamma = (const float*)d_in[7];
    const float* beta  = (const float*)d_in[8];
    const float* fcw   = (const float*)d_in[9];
    const float* fcb   = (const float*)d_in[10];

    float* part = (float*)d_ws;                 // PART_FLOATS floats
    float* acc  = part + PART_FLOATS;           // 18 floats

    hipMemsetAsync(acc, 0, 18 * sizeof(float), stream);
    mbfca_attn<<<dim3(NCB * KS), dim3(256), 0, stream>>>(
        x, WQ, bQv, WK, bKv, WV, bVv, part);
    mbfca_stats<<<dim3(NROW / 256), dim3(256), 0, stream>>>(part, acc);
    mbfca_bnfc<<<dim3(NROW / 256), dim3(256), 0, stream>>>(
        part, acc, gamma, beta, fcw, fcb, (float*)d_out);
}